// Round 2
// baseline (110.136 us; speedup 1.0000x reference)
//
#include <hip/hip_runtime.h>

// KDE gaussian: out[k][b] = (1/(LEN*bw*sqrt(2pi))) * sum_i exp(-0.5*((x[b][i]-c[k])/bw)^2)
// bw = 0.1. Fold into 2^(-(S*(x-c))^2), S = sqrt(0.5*log2(e))/bw, so the inner loop
// is sub/mul/exp2(neg input modifier)/add per pair. float2/float4 shapes encourage
// v_pk_* packed fp32 for the non-trans ops. 2048 blocks -> 8 waves/SIMD latency hiding.

constexpr int KPTS  = 256;  // grid points == blockDim.x
constexpr int CHUNK = 256;  // samples staged per block

__global__ __launch_bounds__(KPTS) void kde_kernel(
    const float* __restrict__ data, const float* __restrict__ c_X,
    float* __restrict__ out, int LEN, int B) {
  __shared__ float xs[CHUNK];

  const int k = threadIdx.x;
  const float S = 8.49321736f;  // sqrt(0.5*log2(e)) / 0.1

  // Stage CHUNK samples (pre-scaled by S): one coalesced load per thread.
  const float* src = data + (size_t)blockIdx.y * LEN + (size_t)blockIdx.x * CHUNK;
  xs[k] = src[k] * S;
  __syncthreads();

  const float cs = c_X[k] * S;

  float2 a0 = {0.f, 0.f}, a1 = {0.f, 0.f}, a2 = {0.f, 0.f}, a3 = {0.f, 0.f};
#pragma unroll 4
  for (int i = 0; i < CHUNK / 8; ++i) {
    float4 p = ((const float4*)xs)[2 * i];      // LDS broadcast, conflict-free
    float4 q = ((const float4*)xs)[2 * i + 1];
    float t0 = p.x - cs, t1 = p.y - cs, t2 = p.z - cs, t3 = p.w - cs;
    float u0 = q.x - cs, u1 = q.y - cs, u2 = q.z - cs, u3 = q.w - cs;
    a0.x += __builtin_amdgcn_exp2f(-(t0 * t0));
    a0.y += __builtin_amdgcn_exp2f(-(t1 * t1));
    a1.x += __builtin_amdgcn_exp2f(-(t2 * t2));
    a1.y += __builtin_amdgcn_exp2f(-(t3 * t3));
    a2.x += __builtin_amdgcn_exp2f(-(u0 * u0));
    a2.y += __builtin_amdgcn_exp2f(-(u1 * u1));
    a3.x += __builtin_amdgcn_exp2f(-(u2 * u2));
    a3.y += __builtin_amdgcn_exp2f(-(u3 * u3));
  }

  const float norm = 3.98942280f / (float)LEN;  // (1/bw)*(1/sqrt(2pi))/LEN
  float s = ((a0.x + a0.y) + (a1.x + a1.y)) + ((a2.x + a2.y) + (a3.x + a3.y));
  atomicAdd(&out[(size_t)k * B + blockIdx.y], s * norm);
}

extern "C" void kernel_launch(void* const* d_in, const int* in_sizes, int n_in,
                              void* d_out, int out_size, void* d_ws, size_t ws_size,
                              hipStream_t stream) {
  const float* data = (const float*)d_in[0];
  // d_in[1] is `dim` (= -1): last-axis reduction, data already [B, LEN]
  const float* c_X  = (const float*)d_in[2];
  float* out        = (float*)d_out;

  const int B   = 16;
  const int LEN = in_sizes[0] / B;  // 32768

  hipMemsetAsync(d_out, 0, (size_t)out_size * sizeof(float), stream);

  dim3 grid(LEN / CHUNK, B);        // (128, 16) = 2048 blocks -> 8 waves/SIMD
  kde_kernel<<<grid, KPTS, 0, stream>>>(data, c_X, out, LEN, B);
}

// Round 3
// 92.582 us; speedup vs baseline: 1.1896x; 1.1896x over previous
//
#include <hip/hip_runtime.h>

// KDE gaussian: out[k][b] = (1/(LEN*bw*sqrt(2pi))) * sum_i exp(-0.5*((x[b][i]-c[k])/bw)^2)
// bw = 0.1. Folded: 2^(-(S*x - S*c)^2), S = sqrt(0.5*log2(e))/bw.
// Per pair: v_fma (t = x*S - cs), v_mul (t*t), v_exp (neg input modifier), v_add.
// No LDS, no barriers: sample loads are wave-uniform -> SMEM s_load (scalar pipe)
// or same-address broadcast global load; either way zero VALU staging cost.
// 16 independent exp chains + float2 accumulators for trans-latency hiding / v_pk_*.

constexpr int KPTS  = 256;  // grid points == blockDim.x
constexpr int CHUNK = 512;  // samples per block

__global__ __launch_bounds__(KPTS) void kde_kernel(
    const float* __restrict__ data, const float* __restrict__ c_X,
    float* __restrict__ out, int LEN, int B) {
  const int k = threadIdx.x;
  const float S = 8.49321736f;  // sqrt(0.5*log2(e)) / 0.1

  const float* src = data + (size_t)blockIdx.y * LEN + (size_t)blockIdx.x * CHUNK;
  const float ncs = -(c_X[k] * S);  // -S*c, per-lane

  float2 a0 = {0.f, 0.f}, a1 = {0.f, 0.f}, a2 = {0.f, 0.f}, a3 = {0.f, 0.f};
  float2 a4 = {0.f, 0.f}, a5 = {0.f, 0.f}, a6 = {0.f, 0.f}, a7 = {0.f, 0.f};

  for (int i = 0; i < CHUNK; i += 16) {
    // Uniform addresses (blockIdx + loop counter only) -> scalar loads.
    const float4* p = (const float4*)(src + i);
    float4 x0 = p[0], x1 = p[1], x2 = p[2], x3 = p[3];

    float t0 = fmaf(x0.x, S, ncs), t1 = fmaf(x0.y, S, ncs);
    float t2 = fmaf(x0.z, S, ncs), t3 = fmaf(x0.w, S, ncs);
    float t4 = fmaf(x1.x, S, ncs), t5 = fmaf(x1.y, S, ncs);
    float t6 = fmaf(x1.z, S, ncs), t7 = fmaf(x1.w, S, ncs);
    float t8 = fmaf(x2.x, S, ncs), t9 = fmaf(x2.y, S, ncs);
    float ta = fmaf(x2.z, S, ncs), tb = fmaf(x2.w, S, ncs);
    float tc = fmaf(x3.x, S, ncs), td = fmaf(x3.y, S, ncs);
    float te = fmaf(x3.z, S, ncs), tf = fmaf(x3.w, S, ncs);

    a0.x += __builtin_amdgcn_exp2f(-(t0 * t0));
    a0.y += __builtin_amdgcn_exp2f(-(t1 * t1));
    a1.x += __builtin_amdgcn_exp2f(-(t2 * t2));
    a1.y += __builtin_amdgcn_exp2f(-(t3 * t3));
    a2.x += __builtin_amdgcn_exp2f(-(t4 * t4));
    a2.y += __builtin_amdgcn_exp2f(-(t5 * t5));
    a3.x += __builtin_amdgcn_exp2f(-(t6 * t6));
    a3.y += __builtin_amdgcn_exp2f(-(t7 * t7));
    a4.x += __builtin_amdgcn_exp2f(-(t8 * t8));
    a4.y += __builtin_amdgcn_exp2f(-(t9 * t9));
    a5.x += __builtin_amdgcn_exp2f(-(ta * ta));
    a5.y += __builtin_amdgcn_exp2f(-(tb * tb));
    a6.x += __builtin_amdgcn_exp2f(-(tc * tc));
    a6.y += __builtin_amdgcn_exp2f(-(td * td));
    a7.x += __builtin_amdgcn_exp2f(-(te * te));
    a7.y += __builtin_amdgcn_exp2f(-(tf * tf));
  }

  const float norm = 3.98942280f / (float)LEN;  // (1/bw)*(1/sqrt(2pi))/LEN
  float2 s01 = {a0.x + a1.x, a0.y + a1.y};
  float2 s23 = {a2.x + a3.x, a2.y + a3.y};
  float2 s45 = {a4.x + a5.x, a4.y + a5.y};
  float2 s67 = {a6.x + a7.x, a6.y + a7.y};
  float2 s = {s01.x + s23.x + s45.x + s67.x, s01.y + s23.y + s45.y + s67.y};
  atomicAdd(&out[(size_t)k * B + blockIdx.y], (s.x + s.y) * norm);
}

extern "C" void kernel_launch(void* const* d_in, const int* in_sizes, int n_in,
                              void* d_out, int out_size, void* d_ws, size_t ws_size,
                              hipStream_t stream) {
  const float* data = (const float*)d_in[0];
  // d_in[1] is `dim` (= -1): last-axis reduction, data already [B, LEN]
  const float* c_X  = (const float*)d_in[2];
  float* out        = (float*)d_out;

  const int B   = 16;
  const int LEN = in_sizes[0] / B;  // 32768

  hipMemsetAsync(d_out, 0, (size_t)out_size * sizeof(float), stream);

  dim3 grid(LEN / CHUNK, B);        // (64, 16) = 1024 blocks, 16 waves/CU
  kde_kernel<<<grid, KPTS, 0, stream>>>(data, c_X, out, LEN, B);
}